// Round 9
// baseline (79.568 us; speedup 1.0000x reference)
//
#include <hip/hip_runtime.h>
#include <hip/hip_bf16.h>

// V[k,d] = sum_n a_bar[k,n]*x[d,n] - c[k,d]*sum_n a_bar[k,n]
// K=64, D=512, N=131072.
// Stage 1: reg-staged bf16-LDS split-N MFMA GEMM, DT=128, BK=64 (256-B row
//          visits), 24KB buffers x2, 3 blocks/CU, register-disciplined
//          (<=5 live frag regs) -> bf16 partials (fragment layout) in d_ws.
// Stage 2: reduce partials + fused c*a_sum epilogue.

#define K_ROWS 64
#define D_COLS 512
#define N_RED  131072LL
#define TOTAL_STEPS 2048          // N / 64 (BK = 64)
#define XBY 16384                 // bf16 x-tile: 128 rows x 64 n x 2B
#define ABY 8192                  // bf16 a-tile:  64 rows x 64 n x 2B
#define BUFB (XBY + ABY)          // 24 KB

typedef __attribute__((ext_vector_type(8))) short short8;
typedef __attribute__((ext_vector_type(4))) float f32x4;

static __device__ __forceinline__ short f2bf(float f) {
    __bf16 h = (__bf16)f;                  // RNE; pairs fuse to v_cvt_pk_bf16_f32
    return __builtin_bit_cast(short, h);
}
static __device__ __forceinline__ float bf2f(unsigned short u) {
    return __builtin_bit_cast(float, (unsigned)u << 16);
}
static __device__ __forceinline__ short8 cvt8(float4 a, float4 b) {
    short8 r;
    r[0] = f2bf(a.x); r[1] = f2bf(a.y); r[2] = f2bf(a.z); r[3] = f2bf(a.w);
    r[4] = f2bf(b.x); r[5] = f2bf(b.y); r[6] = f2bf(b.z); r[7] = f2bf(b.w);
    return r;
}

// Grid: 4*S blocks of 512 threads (8 waves), 48KB LDS, 3 blocks/CU.
// bid = m*32 + g*8 + x7: col-group g (d-cols [g*128,+128)), n-chunk s = m*8+x7
// — the 4 g's of one s share x7 => same XCD (a_bar window L2-shared).
// Uneven step split: block s covers steps [s*2048/S, (s+1)*2048/S).
// LDS tiles bf16, row = 128B = 8 x 16B units, unit ^= row&7 (quad-balanced on
// every ds_write_b128 and ds_read_b128 -> conflict-free).
// Per K-step (64 n): barrier -> issue 6 dwordx4 (256B-contiguous row visits)
// -> [k-half: 5 ds_read_b128 + 4 MFMA] x2 -> vmcnt-wait + cvt + 3 ds_write.
__global__ __launch_bounds__(512, 6) void vlad_stage1(
    const float* __restrict__ x, const float* __restrict__ ab,
    unsigned short* __restrict__ pax, float* __restrict__ pasum, int S)
{
    __shared__ __align__(16) char smem[2][BUFB];

    const int bid = blockIdx.x;
    const int x7  = bid & 7;
    const int g   = (bid >> 3) & 3;
    const int m   = bid >> 5;
    const int s   = m * 8 + x7;
    const int tid = threadIdx.x;
    const int w   = tid >> 6, l = tid & 63, lr = l & 15, lg = l >> 4;
    const int d0  = g * 128;

    const int st0 = (int)(((long long)s       * TOTAL_STEPS) / S);
    const int st1 = (int)(((long long)(s + 1) * TOTAL_STEPS) / S);

    // ---- staging geometry ----
    // x: row tid>>2 (4 thr/row), 16 consecutive f32 at (tid&3)*16 => 256B/row
    const int xrow = tid >> 2, xq = tid & 3;
    const float* gx = x + (size_t)(d0 + xrow) * N_RED + xq * 16;
    const int xo0 = xrow * 128 + (((xq * 2)     ^ (xrow & 7)) << 4);
    const int xo1 = xrow * 128 + (((xq * 2 + 1) ^ (xrow & 7)) << 4);
    // a: row tid>>3 (8 thr/row), 8 consecutive f32 at (tid&7)*8 => 256B/row
    const int arow = tid >> 3, aq = tid & 7;
    const float* ga = ab + (size_t)arow * N_RED + aq * 8;
    const int ao0 = XBY + arow * 128 + ((aq ^ (arow & 7)) << 4);

    // ---- fragment bases (2 per operand; t-tiles via immediate +2048) ----
    const int swz = lr & 7;
    const int fx0 = (w * 16 + lr) * 128 + ((lg ^ swz) << 4);
    const int fx1 = (w * 16 + lr) * 128 + (((4 + lg) ^ swz) << 4);
    const int fa0 = XBY + lr * 128 + ((lg ^ swz) << 4);
    const int fa1 = XBY + lr * 128 + (((4 + lg) ^ swz) << 4);

    f32x4 acc[4] = {};
    float asum = 0.f;
    float4 X0, X1, X2, X3, A0, A1;

    auto issue = [&](int it) {
        const float* p = gx + (size_t)it * 64;
        X0 = *(const float4*)(p);
        X1 = *(const float4*)(p + 4);
        X2 = *(const float4*)(p + 8);
        X3 = *(const float4*)(p + 12);
        const float* q = ga + (size_t)it * 64;
        A0 = *(const float4*)(q);
        A1 = *(const float4*)(q + 4);
    };
    auto commit = [&](char* buf) {
        *(short8*)(buf + xo0) = cvt8(X0, X1);
        *(short8*)(buf + xo1) = cvt8(X2, X3);
        *(short8*)(buf + ao0) = cvt8(A0, A1);
        asum += ((A0.x + A0.y) + (A0.z + A0.w))
              + ((A1.x + A1.y) + (A1.z + A1.w));
    };

    issue(st0);
    commit(smem[0]);

    int cur = 0;
    #pragma unroll 1
    for (int it = st0; it < st1; ++it) {
        const bool more = (it + 1 < st1);
        __syncthreads();              // buf[cur] writes drained; buf[cur^1] free
        if (more) issue(it + 1);      // loads fly under the whole compute phase

        const char* b = smem[cur];
        {   // k-half 0: 5 frag regs live (20 VGPR)
            short8 xf = *(const short8*)(b + fx0);
            short8 f0 = *(const short8*)(b + fa0);
            short8 f1 = *(const short8*)(b + fa0 + 2048);
            short8 f2 = *(const short8*)(b + fa0 + 4096);
            short8 f3 = *(const short8*)(b + fa0 + 6144);
            acc[0] = __builtin_amdgcn_mfma_f32_16x16x32_bf16(f0, xf, acc[0], 0, 0, 0);
            acc[1] = __builtin_amdgcn_mfma_f32_16x16x32_bf16(f1, xf, acc[1], 0, 0, 0);
            acc[2] = __builtin_amdgcn_mfma_f32_16x16x32_bf16(f2, xf, acc[2], 0, 0, 0);
            acc[3] = __builtin_amdgcn_mfma_f32_16x16x32_bf16(f3, xf, acc[3], 0, 0, 0);
        }
        {   // k-half 1
            short8 xf = *(const short8*)(b + fx1);
            short8 f0 = *(const short8*)(b + fa1);
            short8 f1 = *(const short8*)(b + fa1 + 2048);
            short8 f2 = *(const short8*)(b + fa1 + 4096);
            short8 f3 = *(const short8*)(b + fa1 + 6144);
            acc[0] = __builtin_amdgcn_mfma_f32_16x16x32_bf16(f0, xf, acc[0], 0, 0, 0);
            acc[1] = __builtin_amdgcn_mfma_f32_16x16x32_bf16(f1, xf, acc[1], 0, 0, 0);
            acc[2] = __builtin_amdgcn_mfma_f32_16x16x32_bf16(f2, xf, acc[2], 0, 0, 0);
            acc[3] = __builtin_amdgcn_mfma_f32_16x16x32_bf16(f3, xf, acc[3], 0, 0, 0);
        }

        if (more) commit(smem[cur ^ 1]);   // vmcnt wait covers full compute phase
        cur ^= 1;
    }

    // bf16 partials, fragment layout: f = (((g*8+w)*4+t)*4+r)*64 + l
    // (k = t*16+lg*4+r, d = g*128+w*16+lr) — coalesced 128B lines.
    unsigned short* dst = pax + (size_t)s * (K_ROWS * D_COLS);
    #pragma unroll
    for (int t = 0; t < 4; ++t)
        #pragma unroll
        for (int r = 0; r < 4; ++r)
            dst[(((g * 8 + w) * 4 + t) * 4 + r) * 64 + l] =
                (unsigned short)f2bf(acc[t][r]);

    // a_sum partial: 8 stagers per a-row are adjacent lanes (tid&7).
    if (g == 0) {
        asum += __shfl_xor(asum, 1, 64);
        asum += __shfl_xor(asum, 2, 64);
        asum += __shfl_xor(asum, 4, 64);
        if (aq == 0) pasum[s * K_ROWS + arow] = asum;
    }
}

// Grid: 32768/64 = 512 blocks of 256. Block covers 64 consecutive fragment
// indices (fixed g,w,t,r; lg,lr vary): 4-way s-split + LDS combine,
// block-parallel a_sum reduce over the block's 4 k-rows.
__global__ __launch_bounds__(256) void vlad_stage2(
    const unsigned short* __restrict__ pax, const float* __restrict__ pasum,
    const float* __restrict__ c, float* __restrict__ out, int S)
{
    __shared__ float red[256];
    __shared__ float ared[256];
    const int t  = threadIdx.x;
    const int fo = t & 63;
    const int sp = t >> 6;
    const int fb = blockIdx.x * 64;
    const int f  = fb + fo;

    float acc = 0.f;
    for (int s = sp; s < S; s += 4)
        acc += bf2f(pax[(size_t)s * (K_ROWS * D_COLS) + f]);
    red[t] = acc;

    // a_sum partials for this block's 4 k-rows (indexed by lg = t&3)
    const int R = (fb >> 6) & 3, T = (fb >> 8) & 3;
    const int ka = T * 16 + (t & 3) * 4 + R;
    float pa = 0.f;
    for (int s2 = t >> 2; s2 < S; s2 += 64)
        pa += pasum[s2 * K_ROWS + ka];
    ared[t] = pa;
    __syncthreads();

    for (int st = 128; st >= 4; st >>= 1) {
        if (t < st) ared[t] += ared[t + st];
        __syncthreads();
    }
    if (sp == 0) {
        const int lr = f & 15, lg = (f >> 4) & 3;
        const int r  = (f >> 6) & 3, tt = (f >> 8) & 3;
        const int w  = (f >> 10) & 7, gg = (f >> 13) & 3;
        const int k  = tt * 16 + lg * 4 + r;
        const int d  = gg * 128 + w * 16 + lr;
        float v = red[t] + red[t + 64] + red[t + 128] + red[t + 192];
        out[k * D_COLS + d] = v - c[k * D_COLS + d] * ared[lg];
    }
}

extern "C" void kernel_launch(void* const* d_in, const int* in_sizes, int n_in,
                              void* d_out, int out_size, void* d_ws, size_t ws_size,
                              hipStream_t stream)
{
    const float* x  = (const float*)d_in[0];
    const float* ab = (const float*)d_in[1];
    const float* c  = (const float*)d_in[2];
    float* out = (float*)d_out;

    // S=192 -> grid 768 = exactly 3 blocks/CU; halve if ws too small
    // (S must stay a multiple of 8 for the XCD mapping).
    int S = 192;
    while (S > 24 &&
           (size_t)S * ((size_t)K_ROWS * D_COLS * 2 + K_ROWS * 4) > ws_size)
        S >>= 1;

    unsigned short* pax = (unsigned short*)d_ws;
    float* pasum = (float*)((char*)d_ws + (size_t)S * K_ROWS * D_COLS * 2);

    vlad_stage1<<<dim3(4 * S), dim3(512), 0, stream>>>(x, ab, pax, pasum, S);
    vlad_stage2<<<dim3((K_ROWS * D_COLS) / 64), dim3(256), 0, stream>>>(pax, pasum, c, out, S);
}

// Round 10
// 77.946 us; speedup vs baseline: 1.0208x; 1.0208x over previous
//
#include <hip/hip_runtime.h>
#include <hip/hip_bf16.h>

// V[k,d] = sum_n a_bar[k,n]*x[d,n] - c[k,d]*sum_n a_bar[k,n]
// K=64, D=512, N=131072.
// Stage 1: global_load_lds-staged f32 tiles, ring-of-3, 2 steps in flight,
//          counted vmcnt(6) + raw s_barrier (loads NEVER drain in the loop),
//          per-wave x tiles / shared a tile, bf16 MFMA -> bf16 partials.
// Stage 2: reduce partials + fused c*a_sum epilogue.

#define K_ROWS 64
#define D_COLS 512
#define N_RED  131072LL

// LDS layout (72 KB): x: [8 waves][3 bufs][2048B] = 48 KB at 0;
//                     a: [3 bufs][8192B] = 24 KB at 49152.
#define XW     6144
#define ABASE  49152
#define ABUF   8192
#define SMEMSZ 73728

typedef __attribute__((ext_vector_type(8))) short short8;
typedef __attribute__((ext_vector_type(4))) float f32x4;

static __device__ __forceinline__ short f2bf(float f) {
    __bf16 h = (__bf16)f;                  // RNE; pairs fuse to v_cvt_pk_bf16_f32
    return __builtin_bit_cast(short, h);
}
static __device__ __forceinline__ float bf2f(unsigned short u) {
    return __builtin_bit_cast(float, (unsigned)u << 16);
}
static __device__ __forceinline__ short8 cvt8(float4 a, float4 b) {
    short8 r;
    r[0] = f2bf(a.x); r[1] = f2bf(a.y); r[2] = f2bf(a.z); r[3] = f2bf(a.w);
    r[4] = f2bf(b.x); r[5] = f2bf(b.y); r[6] = f2bf(b.z); r[7] = f2bf(b.w);
    return r;
}
static __device__ __forceinline__ void gload16(const float* g, char* l) {
    __builtin_amdgcn_global_load_lds(
        (const __attribute__((address_space(1))) void*)g,
        (__attribute__((address_space(3))) void*)l, 16, 0, 0);
}

// Grid: 4*S blocks of 512 threads (8 waves), 72KB LDS, 2 blocks/CU.
// bid = m*32 + g*8 + x7: col-group g (d-cols [g*128,+128)), n-chunk s = m*8+x7
// — the 4 g's of one s share x7 => same XCD (a_bar window L2-shared).
// Block s covers K-steps [0, chunk/32) of n-window [s*chunk, (s+1)*chunk).
//
// Tiles staged as RAW F32 by global_load_lds: dest is wave-uniform base +
// lane*16 (linear, required); the XOR swizzle (16B unit u of row r holds
// col-unit (u&7)^(r&7)) is baked into the PER-LANE GLOBAL source address.
// Wave w's x rows [w*16,+16) are staged and consumed by wave w only.
//
// Per iter it (ring buf = it%3):
//   issue group it+2: 2 x gload16 + 1 a gload16          (3 VMEM/lane)
//   s_waitcnt vmcnt(6); s_barrier      // group it landed everywhere;
//                                      // groups it+1,it+2 stay in flight
//   compute: 10 ds_read_b128 (f32 frags) + cvt8 + 4 MFMA (+ a_sum read)
//   s_waitcnt lgkmcnt(0); s_barrier    // reads done before slot reuse
__global__ __launch_bounds__(512, 4) void vlad_stage1(
    const float* __restrict__ x, const float* __restrict__ ab,
    unsigned short* __restrict__ pax, float* __restrict__ pasum, int S)
{
    __shared__ __align__(16) char smem[SMEMSZ];

    const int bid = blockIdx.x;
    const int x7  = bid & 7;
    const int g   = (bid >> 3) & 3;
    const int m   = bid >> 5;
    const int s   = m * 8 + x7;
    const int tid = threadIdx.x;
    const int w   = tid >> 6, l = tid & 63, lr = l & 15, lg = l >> 4;
    const int d0  = g * 128;

    const int chunk = (int)(N_RED / S);
    const int nst   = chunk >> 5;                 // K-steps (BK=32)
    const size_t nblk = (size_t)s * chunk;

    // ---- staging sources (per-lane, pre-swizzled) ----
    const int csrc = (((l & 7) ^ (l >> 3)) << 2);          // f32 col offset
    const float* gx0 = x + (size_t)(d0 + w * 16 + (l >> 3)) * N_RED + nblk + csrc;
    const float* gx1 = gx0 + (size_t)8 * N_RED;
    const float* ga  = ab + (size_t)(w * 8 + (l >> 3)) * N_RED + nblk + csrc;

    // ---- fragment read offsets (swizzle matches: row&7 == lr&7) ----
    const int swz = lr & 7;
    int fx[2], fa[4][2];
    #pragma unroll
    for (int h = 0; h < 2; ++h) {
        fx[h] = lr * 128 + (((lg * 2 + h) ^ swz) << 4);
        #pragma unroll
        for (int t = 0; t < 4; ++t)
            fa[t][h] = (t * 16 + lr) * 128 + (((lg * 2 + h) ^ swz) << 4);
    }

    f32x4 acc[4] = {};
    float asum = 0.f;
    const bool g0 = (g == 0);

    auto issue = [&](int it) {
        const int buf = it % 3;                   // uniform (SALU)
        char* xd = smem + w * XW + buf * 2048;
        gload16(gx0 + (size_t)it * 32, xd);
        gload16(gx1 + (size_t)it * 32, xd + 1024);
        gload16(ga  + (size_t)it * 32, smem + ABASE + buf * ABUF + w * 1024);
    };

    issue(0);
    if (nst > 1) issue(1);

    int buf = 0;
    #pragma unroll 1
    for (int it = 0; it < nst; ++it) {
        if (it + 2 < nst) issue(it + 2);
        // counted wait + barrier in ONE asm block: group it landed for every
        // wave before anyone reads; up to 6 newer loads stay in flight.
        if (it + 2 < nst)      asm volatile("s_waitcnt vmcnt(6)\ns_barrier" ::: "memory");
        else if (it + 1 < nst) asm volatile("s_waitcnt vmcnt(3)\ns_barrier" ::: "memory");
        else                   asm volatile("s_waitcnt vmcnt(0)\ns_barrier" ::: "memory");

        const char* bx = smem + w * XW + buf * 2048;
        const char* ba = smem + ABASE + buf * ABUF;

        float4 xl = *(const float4*)(bx + fx[0]);
        float4 xh = *(const float4*)(bx + fx[1]);
        short8 xf = cvt8(xl, xh);
        #pragma unroll
        for (int t = 0; t < 4; ++t) {
            float4 al = *(const float4*)(ba + fa[t][0]);
            float4 ah = *(const float4*)(ba + fa[t][1]);
            acc[t] = __builtin_amdgcn_mfma_f32_16x16x32_bf16(
                         cvt8(al, ah), xf, acc[t], 0, 0, 0);
        }
        if (g0) {   // a_sum: raw 16B unit of row tid>>3 (order-agnostic sum)
            float4 av = *(const float4*)(ba + tid * 16);
            asum += (av.x + av.y) + (av.z + av.w);
        }

        // reads of buf done before its slot is re-issued next iteration
        asm volatile("s_waitcnt lgkmcnt(0)\ns_barrier" ::: "memory");
        buf = (buf + 1 == 3) ? 0 : buf + 1;
    }

    // bf16 partials, fragment layout: f = (((g*8+w)*4+t)*4+r)*64 + l
    // (k = t*16+lg*4+r, d = g*128+w*16+lr) — coalesced 128B lines.
    unsigned short* dst = pax + (size_t)s * (K_ROWS * D_COLS);
    #pragma unroll
    for (int t = 0; t < 4; ++t)
        #pragma unroll
        for (int r = 0; r < 4; ++r)
            dst[(((g * 8 + w) * 4 + t) * 4 + r) * 64 + l] =
                (unsigned short)f2bf(acc[t][r]);

    // a_sum partial: 8 readers per a-row are adjacent lanes (tid&7).
    if (g0) {
        asum += __shfl_xor(asum, 1, 64);
        asum += __shfl_xor(asum, 2, 64);
        asum += __shfl_xor(asum, 4, 64);
        if ((tid & 7) == 0) pasum[s * K_ROWS + (tid >> 3)] = asum;
    }
}

// Grid: 32768/64 = 512 blocks of 256. Block covers 64 consecutive fragment
// indices (fixed g,w,t,r; lg,lr vary): 4-way s-split + LDS combine,
// block-parallel a_sum reduce over the block's 4 k-rows.
__global__ __launch_bounds__(256) void vlad_stage2(
    const unsigned short* __restrict__ pax, const float* __restrict__ pasum,
    const float* __restrict__ c, float* __restrict__ out, int S)
{
    __shared__ float red[256];
    __shared__ float ared[256];
    const int t  = threadIdx.x;
    const int fo = t & 63;
    const int sp = t >> 6;
    const int fb = blockIdx.x * 64;
    const int f  = fb + fo;

    float acc = 0.f;
    for (int s = sp; s < S; s += 4)
        acc += bf2f(pax[(size_t)s * (K_ROWS * D_COLS) + f]);
    red[t] = acc;

    // a_sum partials for this block's 4 k-rows (indexed by lg = t&3)
    const int R = (fb >> 6) & 3, T = (fb >> 8) & 3;
    const int ka = T * 16 + (t & 3) * 4 + R;
    float pa = 0.f;
    for (int s2 = t >> 2; s2 < S; s2 += 64)
        pa += pasum[s2 * K_ROWS + ka];
    ared[t] = pa;
    __syncthreads();

    for (int st = 128; st >= 4; st >>= 1) {
        if (t < st) ared[t] += ared[t + st];
        __syncthreads();
    }
    if (sp == 0) {
        const int lr = f & 15, lg = (f >> 4) & 3;
        const int r  = (f >> 6) & 3, tt = (f >> 8) & 3;
        const int w  = (f >> 10) & 7, gg = (f >> 13) & 3;
        const int k  = tt * 16 + lg * 4 + r;
        const int d  = gg * 128 + w * 16 + lr;
        float v = red[t] + red[t + 64] + red[t + 128] + red[t + 192];
        out[k * D_COLS + d] = v - c[k * D_COLS + d] * ared[lg];
    }
}

extern "C" void kernel_launch(void* const* d_in, const int* in_sizes, int n_in,
                              void* d_out, int out_size, void* d_ws, size_t ws_size,
                              hipStream_t stream)
{
    const float* x  = (const float*)d_in[0];
    const float* ab = (const float*)d_in[1];
    const float* c  = (const float*)d_in[2];
    float* out = (float*)d_out;

    // S=128 -> grid 512 = exactly 2 blocks/CU, 32 uniform K-steps per block.
    int S = 128;
    while (S > 8 &&
           (size_t)S * ((size_t)K_ROWS * D_COLS * 2 + K_ROWS * 4) > ws_size)
        S >>= 1;

    unsigned short* pax = (unsigned short*)d_ws;
    float* pasum = (float*)((char*)d_ws + (size_t)S * K_ROWS * D_COLS * 2);

    vlad_stage1<<<dim3(4 * S), dim3(512), 0, stream>>>(x, ab, pax, pasum, S);
    vlad_stage2<<<dim3((K_ROWS * D_COLS) / 64), dim3(256), 0, stream>>>(pax, pasum, c, out, S);
}

// Round 11
// 77.925 us; speedup vs baseline: 1.0211x; 1.0003x over previous
//
#include <hip/hip_runtime.h>
#include <hip/hip_bf16.h>

// V[k,d] = sum_n a_bar[k,n]*x[d,n] - c[k,d]*sum_n a_bar[k,n]
// K=64, D=512, N=131072.
// Stage 1: reg-staged bf16-LDS split-N MFMA GEMM. 256-thread blocks (4 waves),
//          DT=64, BK=32, 8KB buffers x2 -> 6 blocks/CU (max independent
//          barrier domains). Issue-early/commit-late. bf16 partials -> d_ws.
// Stage 2: reduce partials + fused c*a_sum epilogue.

#define K_ROWS 64
#define D_COLS 512
#define N_RED  131072LL
#define TOTAL_STEPS 4096          // N / 32 (BK = 32)
#define XBY 4096                  // bf16 x-tile: 64 rows x 32 n x 2B
#define ABY 4096                  // bf16 a-tile: 64 rows x 32 n x 2B
#define BUFB (XBY + ABY)          // 8 KB

typedef __attribute__((ext_vector_type(8))) short short8;
typedef __attribute__((ext_vector_type(4))) float f32x4;

static __device__ __forceinline__ short f2bf(float f) {
    __bf16 h = (__bf16)f;                  // RNE; pairs fuse to v_cvt_pk_bf16_f32
    return __builtin_bit_cast(short, h);
}
static __device__ __forceinline__ float bf2f(unsigned short u) {
    return __builtin_bit_cast(float, (unsigned)u << 16);
}
static __device__ __forceinline__ short8 cvt8(float4 a, float4 b) {
    short8 r;
    r[0] = f2bf(a.x); r[1] = f2bf(a.y); r[2] = f2bf(a.z); r[3] = f2bf(a.w);
    r[4] = f2bf(b.x); r[5] = f2bf(b.y); r[6] = f2bf(b.z); r[7] = f2bf(b.w);
    return r;
}

// Grid: 8*S blocks of 256 threads (4 waves), 16KB LDS, 6 blocks/CU.
// bid = m*64 + g*8 + x7: col-group g in 0..7 (d-cols [g*64,+64)), n-chunk
// s = m*8 + x7 — the 8 g's of one s share x7 => same XCD (a_bar L2-shared;
// a re-reads have been L2/L3-absorbed every round: FETCH ~= x only).
// Uneven step split: block s covers steps [s*4096/S, (s+1)*4096/S).
// LDS tiles bf16, row = 64B = 4 x 16B units, unit ^= row&3 (quad-balanced on
// every ds_write_b128 / ds_read_b128 -> conflict-free; verified r5 scheme).
// Per K-step: barrier -> issue 4 dwordx4 (next step) -> 5 ds_read_b128 +
// 4 MFMA -> vmcnt-wait + cvt + 2 ds_write_b128 into the other buffer.
__global__ __launch_bounds__(256, 6) void vlad_stage1(
    const float* __restrict__ x, const float* __restrict__ ab,
    unsigned short* __restrict__ pax, float* __restrict__ pasum, int S)
{
    __shared__ __align__(16) char smem[2][BUFB];

    const int bid = blockIdx.x;
    const int x7  = bid & 7;
    const int g   = (bid >> 3) & 7;
    const int m   = bid >> 6;
    const int s   = m * 8 + x7;
    const int tid = threadIdx.x;
    const int w   = tid >> 6, l = tid & 63, lr = l & 15, lg = l >> 4;
    const int d0  = g * 64;

    const int st0 = (int)(((long long)s       * TOTAL_STEPS) / S);
    const int st1 = (int)(((long long)(s + 1) * TOTAL_STEPS) / S);

    // ---- staging geometry: row = tid>>2 (4 stagers/row), 8 f32 at (tid&3)*8
    const int row = tid >> 2, q = tid & 3;
    const float* gx = x  + (size_t)(d0 + row) * N_RED + q * 8;
    const float* ga = ab + (size_t)row        * N_RED + q * 8;
    const int xo = row * 64 + ((q ^ (row & 3)) << 4);
    const int ao = XBY + xo;

    // ---- fragment read offsets (swizzle matches staging; row&3 == lr&3) ----
    const int swz = lr & 3;
    const int fx = (w * 16 + lr) * 64 + ((lg ^ swz) << 4);
    int fa[4];
    #pragma unroll
    for (int t = 0; t < 4; ++t)
        fa[t] = XBY + (t * 16 + lr) * 64 + ((lg ^ swz) << 4);

    f32x4 acc[4] = {};
    float asum = 0.f;
    float4 X0, X1, A0, A1;

    auto issue = [&](int it) {
        const float* p = gx + (size_t)it * 32;
        X0 = *(const float4*)(p);
        X1 = *(const float4*)(p + 4);
        const float* qq = ga + (size_t)it * 32;
        A0 = *(const float4*)(qq);
        A1 = *(const float4*)(qq + 4);
    };
    auto commit = [&](char* buf) {
        *(short8*)(buf + xo) = cvt8(X0, X1);
        *(short8*)(buf + ao) = cvt8(A0, A1);
        asum += ((A0.x + A0.y) + (A0.z + A0.w))
              + ((A1.x + A1.y) + (A1.z + A1.w));
    };

    issue(st0);
    commit(smem[0]);

    int cur = 0;
    #pragma unroll 1
    for (int it = st0; it < st1; ++it) {
        const bool more = (it + 1 < st1);
        __syncthreads();              // buf[cur] writes drained; buf[cur^1] free
        if (more) issue(it + 1);      // loads fly under the compute phase

        const char* b = smem[cur];
        short8 xf  = *(const short8*)(b + fx);
        short8 a0f = *(const short8*)(b + fa[0]);
        short8 a1f = *(const short8*)(b + fa[1]);
        short8 a2f = *(const short8*)(b + fa[2]);
        short8 a3f = *(const short8*)(b + fa[3]);
        acc[0] = __builtin_amdgcn_mfma_f32_16x16x32_bf16(a0f, xf, acc[0], 0, 0, 0);
        acc[1] = __builtin_amdgcn_mfma_f32_16x16x32_bf16(a1f, xf, acc[1], 0, 0, 0);
        acc[2] = __builtin_amdgcn_mfma_f32_16x16x32_bf16(a2f, xf, acc[2], 0, 0, 0);
        acc[3] = __builtin_amdgcn_mfma_f32_16x16x32_bf16(a3f, xf, acc[3], 0, 0, 0);

        if (more) commit(smem[cur ^ 1]);   // cvt waits vmcnt; write-late
        cur ^= 1;
    }

    // bf16 partials, fragment layout: f = (((g*4+w)*4+t)*4+r)*64 + l
    // (k = t*16+lg*4+r, d = g*64+w*16+lr) — coalesced 128B lines.
    unsigned short* dst = pax + (size_t)s * (K_ROWS * D_COLS);
    #pragma unroll
    for (int t = 0; t < 4; ++t)
        #pragma unroll
        for (int r = 0; r < 4; ++r)
            dst[(((g * 4 + w) * 4 + t) * 4 + r) * 64 + l] =
                (unsigned short)f2bf(acc[t][r]);

    // a_sum partial: 4 stagers per a-row are adjacent lanes (tid&3).
    if (g == 0) {
        asum += __shfl_xor(asum, 1, 64);
        asum += __shfl_xor(asum, 2, 64);
        if (q == 0) pasum[s * K_ROWS + row] = asum;
    }
}

// Grid: 32768/64 = 512 blocks of 256. Block covers 64 consecutive fragment
// indices (fixed g,w,t,r; lg,lr vary): 4-way s-split + LDS combine,
// block-parallel a_sum reduce over the block's 4 k-rows.
__global__ __launch_bounds__(256) void vlad_stage2(
    const unsigned short* __restrict__ pax, const float* __restrict__ pasum,
    const float* __restrict__ c, float* __restrict__ out, int S)
{
    __shared__ float red[256];
    __shared__ float ared[256];
    const int t  = threadIdx.x;
    const int fo = t & 63;
    const int sp = t >> 6;
    const int fb = blockIdx.x * 64;
    const int f  = fb + fo;

    float acc = 0.f;
    for (int s = sp; s < S; s += 4)
        acc += bf2f(pax[(size_t)s * (K_ROWS * D_COLS) + f]);
    red[t] = acc;

    // a_sum partials for this block's 4 k-rows (indexed by lg = t&3)
    const int R = (fb >> 6) & 3, T = (fb >> 8) & 3;
    const int ka = T * 16 + (t & 3) * 4 + R;
    float pa = 0.f;
    for (int s2 = t >> 2; s2 < S; s2 += 64)
        pa += pasum[s2 * K_ROWS + ka];
    ared[t] = pa;
    __syncthreads();

    for (int st = 128; st >= 4; st >>= 1) {
        if (t < st) ared[t] += ared[t + st];
        __syncthreads();
    }
    if (sp == 0) {
        const int lr = f & 15, lg = (f >> 4) & 3;
        const int r  = (f >> 6) & 3, tt = (f >> 8) & 3;
        const int w  = (f >> 10) & 3, gg = (f >> 12) & 7;
        const int k  = tt * 16 + lg * 4 + r;
        const int d  = gg * 64 + w * 16 + lr;
        float v = red[t] + red[t + 64] + red[t + 128] + red[t + 192];
        out[k * D_COLS + d] = v - c[k * D_COLS + d] * ared[lg];
    }
}

extern "C" void kernel_launch(void* const* d_in, const int* in_sizes, int n_in,
                              void* d_out, int out_size, void* d_ws, size_t ws_size,
                              hipStream_t stream)
{
    const float* x  = (const float*)d_in[0];
    const float* ab = (const float*)d_in[1];
    const float* c  = (const float*)d_in[2];
    float* out = (float*)d_out;

    // S=192 -> grid 1536 = exactly 6 blocks/CU; halve if ws too small
    // (S must stay a multiple of 8 for the XCD mapping).
    int S = 192;
    while (S > 24 &&
           (size_t)S * ((size_t)K_ROWS * D_COLS * 2 + K_ROWS * 4) > ws_size)
        S >>= 1;

    unsigned short* pax = (unsigned short*)d_ws;
    float* pasum = (float*)((char*)d_ws + (size_t)S * K_ROWS * D_COLS * 2);

    vlad_stage1<<<dim3(8 * S), dim3(256), 0, stream>>>(x, ab, pax, pasum, S);
    vlad_stage2<<<dim3((K_ROWS * D_COLS) / 64), dim3(256), 0, stream>>>(pax, pasum, c, out, S);
}

// Round 12
// 71.154 us; speedup vs baseline: 1.1182x; 1.0952x over previous
//
#include <hip/hip_runtime.h>
#include <hip/hip_bf16.h>

// V[k,d] = sum_n a_bar[k,n]*x[d,n] - c[k,d]*sum_n a_bar[k,n]
// K=64, D=512, N=131072.
// ROUND 5 STRUCTURE (best measured: 71.8 us total) — reverted verbatim.
// Stage 1: reg-staged bf16-LDS split-N MFMA GEMM, 12KB buffers x2, 3 blocks/CU,
//          issue-early/write-late -> bf16 partials (fragment layout) in d_ws.
// Stage 2: reduce partials + fused c*a_sum epilogue.

#define K_ROWS 64
#define D_COLS 512
#define N_RED  131072LL
#define TOTAL_STEPS 4096          // N / 32
#define XBY 8192                  // bf16 x-tile: 128 rows x 32 n x 2B
#define ABY 4096                  // bf16 a-tile:  64 rows x 32 n x 2B
#define BUFB (XBY + ABY)          // 12 KB

typedef __attribute__((ext_vector_type(8))) short short8;
typedef __attribute__((ext_vector_type(4))) float f32x4;

static __device__ __forceinline__ short f2bf(float f) {
    __bf16 h = (__bf16)f;                  // RNE; pairs fuse to v_cvt_pk_bf16_f32
    return __builtin_bit_cast(short, h);
}
static __device__ __forceinline__ float bf2f(unsigned short u) {
    return __builtin_bit_cast(float, (unsigned)u << 16);
}
static __device__ __forceinline__ short8 cvt8(float4 a, float4 b) {
    short8 r;
    r[0] = f2bf(a.x); r[1] = f2bf(a.y); r[2] = f2bf(a.z); r[3] = f2bf(a.w);
    r[4] = f2bf(b.x); r[5] = f2bf(b.y); r[6] = f2bf(b.z); r[7] = f2bf(b.w);
    return r;
}

// Grid: 4*S blocks of 512 threads (8 waves), 24KB LDS, 3 blocks/CU.
// bid = m*32 + g*8 + x7:  col-group g in 0..3 (d-cols [g*128,+128)),
// n-chunk s = m*8 + x7 — the 4 g's of one s share x7 => same XCD (a_bar
// window L2-shared). Uneven K-step split: block s covers steps
// [s*4096/S, (s+1)*4096/S).
// LDS tiles bf16, row = 64B = 4 x 16B units, unit slot ^= (row>>1)&3
// (2-way banks max on both ds_write_b128 and frag ds_read_b128).
// Per K-step: barrier -> issue next loads -> 5 ds_read + 4 MFMA ->
// cvt + ds_write next buffer.
__global__ __launch_bounds__(512, 6) void vlad_stage1(
    const float* __restrict__ x, const float* __restrict__ ab,
    unsigned short* __restrict__ pax, float* __restrict__ pasum, int S)
{
    __shared__ __align__(16) char smem[2][BUFB];

    const int bid = blockIdx.x;
    const int x7  = bid & 7;
    const int g   = (bid >> 3) & 3;
    const int m   = bid >> 5;
    const int s   = m * 8 + x7;
    const int tid = threadIdx.x;
    const int w   = tid >> 6, l = tid & 63, lr = l & 15, lg = l >> 4;
    const int d0  = g * 128;

    const int st0 = (int)(((long long)s       * TOTAL_STEPS) / S);
    const int st1 = (int)(((long long)(s + 1) * TOTAL_STEPS) / S);

    // ---- staging geometry: thread owns one 16B bf16 unit of x (and a if tid<256)
    const int xrow = tid >> 2, xslot = tid & 3;
    const int xoff = xrow * 64 + ((xslot ^ ((xrow >> 1) & 3)) << 4);
    const float* gx = x + (size_t)(d0 + xrow) * N_RED + xslot * 8;

    const int aoff = XBY + xrow * 64 + ((xslot ^ ((xrow >> 1) & 3)) << 4);
    const float* ga = ab + (size_t)xrow * N_RED + xslot * 8;   // valid tid<256
    const bool at = (tid < 256);

    // ---- fragment read offsets (swizzle matches staging; row>>1&3 == lr>>1&3
    //      because 16-row fragment blocks are 16-aligned)
    const int swz = (lr >> 1) & 3;
    const int fxo = (w * 16 + lr) * 64 + ((lg ^ swz) << 4);
    int fao[4];
    #pragma unroll
    for (int t = 0; t < 4; ++t)
        fao[t] = XBY + (t * 16 + lr) * 64 + ((lg ^ swz) << 4);

    f32x4 acc[4] = {};
    float asum = 0.f;
    float4 L0, L1, L2, L3;

    auto issue = [&](int it) {
        const float* p = gx + (size_t)it * 32;
        L0 = *(const float4*)(p);
        L1 = *(const float4*)(p + 4);
        if (at) {
            const float* q = ga + (size_t)it * 32;
            L2 = *(const float4*)(q);
            L3 = *(const float4*)(q + 4);
        }
    };
    auto commit = [&](char* buf) {
        *(short8*)(buf + xoff) = cvt8(L0, L1);
        if (at) {
            *(short8*)(buf + aoff) = cvt8(L2, L3);
            float ssum = ((L2.x + L2.y) + (L2.z + L2.w))
                       + ((L3.x + L3.y) + (L3.z + L3.w));
            ssum += __shfl_xor(ssum, 1, 64);     // reduce the 4 slots of a row
            ssum += __shfl_xor(ssum, 2, 64);
            asum += ssum;
        }
    };

    issue(st0);
    commit(smem[0]);

    int cur = 0;
    #pragma unroll 1
    for (int it = st0; it < st1; ++it) {
        const bool more = (it + 1 < st1);
        __syncthreads();              // buf[cur] writes drained; buf[cur^1] free
        if (more) issue(it + 1);      // loads fly under the MFMA phase (T14)

        const char* b = smem[cur];
        short8 xf  = *(const short8*)(b + fxo);
        short8 a0f = *(const short8*)(b + fao[0]);
        short8 a1f = *(const short8*)(b + fao[1]);
        short8 a2f = *(const short8*)(b + fao[2]);
        short8 a3f = *(const short8*)(b + fao[3]);
        acc[0] = __builtin_amdgcn_mfma_f32_16x16x32_bf16(a0f, xf, acc[0], 0, 0, 0);
        acc[1] = __builtin_amdgcn_mfma_f32_16x16x32_bf16(a1f, xf, acc[1], 0, 0, 0);
        acc[2] = __builtin_amdgcn_mfma_f32_16x16x32_bf16(a2f, xf, acc[2], 0, 0, 0);
        acc[3] = __builtin_amdgcn_mfma_f32_16x16x32_bf16(a3f, xf, acc[3], 0, 0, 0);

        if (more) commit(smem[cur ^ 1]);   // cvt waits vmcnt; write-late
        cur ^= 1;
    }

    // bf16 partials, fragment-layout: f = (((g*8+w)*4+t)*4+r)*64 + l
    // (k = t*16+lg*4+r, d = g*128+w*16+lr) — coalesced 128B lines.
    unsigned short* dst = pax + (size_t)s * (K_ROWS * D_COLS);
    #pragma unroll
    for (int t = 0; t < 4; ++t)
        #pragma unroll
        for (int r = 0; r < 4; ++r)
            dst[(((g * 8 + w) * 4 + t) * 4 + r) * 64 + l] =
                (unsigned short)f2bf(acc[t][r]);

    // a_sum: tid<256 staged a-row (tid>>2); quad already reduced each step.
    if (g == 0 && at && (tid & 3) == 0)
        pasum[s * K_ROWS + (tid >> 2)] = asum;
}

// Grid: 32768/64 = 512 blocks of 256. Block covers 64 consecutive fragment
// indices (fixed g,w,t,r; lg,lr vary): 4-way s-split + LDS combine,
// block-parallel a_sum reduce over the block's 4 k-rows.
__global__ __launch_bounds__(256) void vlad_stage2(
    const unsigned short* __restrict__ pax, const float* __restrict__ pasum,
    const float* __restrict__ c, float* __restrict__ out, int S)
{
    __shared__ float red[256];
    __shared__ float ared[256];
    const int t  = threadIdx.x;
    const int fo = t & 63;
    const int sp = t >> 6;
    const int fb = blockIdx.x * 64;
    const int f  = fb + fo;

    float acc = 0.f;
    for (int s = sp; s < S; s += 4)
        acc += bf2f(pax[(size_t)s * (K_ROWS * D_COLS) + f]);
    red[t] = acc;

    // a_sum partials for this block's 4 k-rows (indexed by lg = t&3)
    const int R = (fb >> 6) & 3, T = (fb >> 8) & 3;
    const int ka = T * 16 + (t & 3) * 4 + R;
    float pa = 0.f;
    for (int s2 = t >> 2; s2 < S; s2 += 64)
        pa += pasum[s2 * K_ROWS + ka];
    ared[t] = pa;
    __syncthreads();

    for (int st = 128; st >= 4; st >>= 1) {
        if (t < st) ared[t] += ared[t + st];
        __syncthreads();
    }
    if (sp == 0) {
        const int lr = f & 15, lg = (f >> 4) & 3;
        const int r  = (f >> 6) & 3, tt = (f >> 8) & 3;
        const int w  = (f >> 10) & 7, gg = (f >> 13) & 3;
        const int k  = tt * 16 + lg * 4 + r;
        const int d  = gg * 128 + w * 16 + lr;
        float v = red[t] + red[t + 64] + red[t + 128] + red[t + 192];
        out[k * D_COLS + d] = v - c[k * D_COLS + d] * ared[lg];
    }
}

extern "C" void kernel_launch(void* const* d_in, const int* in_sizes, int n_in,
                              void* d_out, int out_size, void* d_ws, size_t ws_size,
                              hipStream_t stream)
{
    const float* x  = (const float*)d_in[0];
    const float* ab = (const float*)d_in[1];
    const float* c  = (const float*)d_in[2];
    float* out = (float*)d_out;

    // S=192 -> grid 768 = exactly 3 blocks/CU; halve if ws too small
    // (S must stay a multiple of 8 for the XCD mapping).
    int S = 192;
    while (S > 24 &&
           (size_t)S * ((size_t)K_ROWS * D_COLS * 2 + K_ROWS * 4) > ws_size)
        S >>= 1;

    unsigned short* pax = (unsigned short*)d_ws;
    float* pasum = (float*)((char*)d_ws + (size_t)S * K_ROWS * D_COLS * 2);

    vlad_stage1<<<dim3(4 * S), dim3(512), 0, stream>>>(x, ab, pax, pasum, S);
    vlad_stage2<<<dim3((K_ROWS * D_COLS) / 64), dim3(256), 0, stream>>>(pax, pasum, c, out, S);
}